// Round 1
// baseline (352.622 us; speedup 1.0000x reference)
//
#include <hip/hip_runtime.h>
#include <math.h>

// ---------------- problem constants ----------------
#define BATCH 16
#define IH 384
#define IW 512
#define C1 10
#define P1H 191   // pooled H after conv1(382) / 2
#define P1W 255   // pooled W after conv1(510) / 2
#define C2 16
#define H2 189
#define W2 253
#define C3 32
#define H3 187
#define W3 251
#define N3 (H3*W3)        // 46937
#define KP 128
#define CAP 7680          // max candidates kept for NMS (LDS-resident)
#define NEGV (-1e30f)

// ------------- kernel 1: conv1(3->10,3x3) + PReLU + maxpool2 -------------
// one thread per (b, pool_y, pool_x); computes all 10 channels.
__global__ __launch_bounds__(256) void k_conv1pool(
        const float* __restrict__ im, const float* __restrict__ w,
        const float* __restrict__ bia, const float* __restrict__ slope,
        float* __restrict__ outp) {
    int x = blockIdx.x * 16 + threadIdx.x;
    int y = blockIdx.y * 16 + threadIdx.y;
    int bb = blockIdx.z;
    if (x >= P1W || y >= P1H) return;

    float in[3][4][4];
    #pragma unroll
    for (int ci = 0; ci < 3; ++ci) {
        const float* p = im + (((size_t)bb * 3 + ci) * IH + 2 * y) * IW + 2 * x;
        #pragma unroll
        for (int r = 0; r < 4; ++r) {
            const float2* q = (const float2*)(p + (size_t)r * IW);  // 8B-aligned (2x even)
            float2 a0 = q[0], a1 = q[1];
            in[ci][r][0] = a0.x; in[ci][r][1] = a0.y;
            in[ci][r][2] = a1.x; in[ci][r][3] = a1.y;
        }
    }
    // normalize once, like the reference
    #pragma unroll
    for (int ci = 0; ci < 3; ++ci)
        #pragma unroll
        for (int r = 0; r < 4; ++r)
            #pragma unroll
            for (int c = 0; c < 4; ++c)
                in[ci][r][c] = (in[ci][r][c] - 127.5f) * 0.0078125f;

    for (int oc = 0; oc < C1; ++oc) {   // dynamic loop keeps I$ small
        const float* wo = w + oc * 27;  // uniform address -> scalar loads
        float bv = bia[oc], sv = slope[oc];
        float best = -INFINITY;
        #pragma unroll
        for (int py = 0; py < 2; ++py)
            #pragma unroll
            for (int px = 0; px < 2; ++px) {
                float acc = bv;
                #pragma unroll
                for (int ci = 0; ci < 3; ++ci)
                    #pragma unroll
                    for (int ky = 0; ky < 3; ++ky)
                        #pragma unroll
                        for (int kx = 0; kx < 3; ++kx)
                            acc += in[ci][py + ky][px + kx] * wo[(ci * 3 + ky) * 3 + kx];
                float v = acc > 0.f ? acc : sv * acc;   // PReLU then pool-max (exact order)
                best = fmaxf(best, v);
            }
        outp[(((size_t)bb * C1 + oc) * P1H + y) * P1W + x] = best;
    }
}

// ------------- kernel 2: conv2(10->16,3x3) + PReLU -------------
__global__ __launch_bounds__(256) void k_conv2(
        const float* __restrict__ inp, const float* __restrict__ w,
        const float* __restrict__ bia, const float* __restrict__ slope,
        float* __restrict__ outp) {
    int x = blockIdx.x * 16 + threadIdx.x;
    int y = blockIdx.y * 16 + threadIdx.y;
    int bb = blockIdx.z;
    if (x >= W2 || y >= H2) return;

    float acc[C2];
    #pragma unroll
    for (int oc = 0; oc < C2; ++oc) acc[oc] = bia[oc];

    for (int ci = 0; ci < C1; ++ci) {
        const float* p = inp + (((size_t)bb * C1 + ci) * P1H + y) * P1W + x;
        float v[9];
        #pragma unroll
        for (int ky = 0; ky < 3; ++ky)
            #pragma unroll
            for (int kx = 0; kx < 3; ++kx)
                v[ky * 3 + kx] = p[(size_t)ky * P1W + kx];
        const float* wc = w + ci * 9;
        #pragma unroll
        for (int oc = 0; oc < C2; ++oc) {
            const float* wo = wc + oc * (C1 * 9);
            #pragma unroll
            for (int k = 0; k < 9; ++k) acc[oc] += v[k] * wo[k];
        }
    }
    #pragma unroll
    for (int oc = 0; oc < C2; ++oc) {
        float a = acc[oc];
        outp[(((size_t)bb * C2 + oc) * H2 + y) * W2 + x] = a > 0.f ? a : slope[oc] * a;
    }
}

// ------------- kernel 3: conv3(16->32,3x3)+PReLU + heads + softmax + mask ----
__global__ __launch_bounds__(256) void k_conv3heads(
        const float* __restrict__ inp, const float* __restrict__ w3,
        const float* __restrict__ b3, const float* __restrict__ s3,
        const float* __restrict__ w41, const float* __restrict__ b41,
        const float* __restrict__ w42, const float* __restrict__ b42,
        float* __restrict__ scores, float4* __restrict__ regf) {
    int x = blockIdx.x * 16 + threadIdx.x;
    int y = blockIdx.y * 16 + threadIdx.y;
    int bb = blockIdx.z;
    if (x >= W3 || y >= H3) return;

    float acc[C3];
    #pragma unroll
    for (int oc = 0; oc < C3; ++oc) acc[oc] = b3[oc];

    for (int ci = 0; ci < C2; ++ci) {
        const float* p = inp + (((size_t)bb * C2 + ci) * H2 + y) * W2 + x;
        float v[9];
        #pragma unroll
        for (int ky = 0; ky < 3; ++ky)
            #pragma unroll
            for (int kx = 0; kx < 3; ++kx)
                v[ky * 3 + kx] = p[(size_t)ky * W2 + kx];
        const float* wc = w3 + ci * 9;
        #pragma unroll
        for (int oc = 0; oc < C3; ++oc) {
            const float* wo = wc + oc * (C2 * 9);
            #pragma unroll
            for (int k = 0; k < 9; ++k) acc[oc] += v[k] * wo[k];
        }
    }
    #pragma unroll
    for (int oc = 0; oc < C3; ++oc) {
        float a = acc[oc];
        acc[oc] = a > 0.f ? a : s3[oc] * a;
    }

    float l0 = b41[0], l1 = b41[1];
    #pragma unroll
    for (int c = 0; c < C3; ++c) { l0 += acc[c] * w41[c]; l1 += acc[c] * w41[C3 + c]; }
    float m = fmaxf(l0, l1);
    float e0 = expf(l0 - m), e1 = expf(l1 - m);
    float p1v = e1 / (e0 + e1);

    int n = y * W3 + x;
    scores[(size_t)bb * N3 + n] = (p1v >= 0.6f) ? p1v : NEGV;

    float r0 = b42[0], r1 = b42[1], r2 = b42[2], r3 = b42[3];
    #pragma unroll
    for (int c = 0; c < C3; ++c) {
        r0 += acc[c] * w42[c];
        r1 += acc[c] * w42[C3 + c];
        r2 += acc[c] * w42[2 * C3 + c];
        r3 += acc[c] * w42[3 * C3 + c];
    }
    regf[(size_t)bb * N3 + n] = make_float4(r0, r1, r2, r3);
}

// ------------- kernel 4: per-image NMS (LDS-resident) + box refine -------------
// one block of 1024 threads per image.
__global__ __launch_bounds__(1024) void k_nms(
        const float* __restrict__ scores, const float4* __restrict__ regf,
        float* __restrict__ outp) {
    __shared__ float s_score[CAP];
    __shared__ int   s_idx[CAP];     // also reused as 2048-bin histogram
    __shared__ float r_s[16];
    __shared__ int   r_i[16];
    __shared__ float s_picks[KP];
    __shared__ int   s_picki[KP];
    __shared__ int   s_misc[4];      // 0: M, 1: compact cursor, 2: cutoff bin

    int tid = threadIdx.x;
    int bb = blockIdx.x;
    const float* sc = scores + (size_t)bb * N3;

    if (tid < 4) s_misc[tid] = 0;
    __syncthreads();

    // count candidates (masked scores are >=0.6 or -1e30)
    int cnt = 0;
    for (int i = tid; i < N3; i += 1024) if (sc[i] > 0.f) cnt++;
    atomicAdd(&s_misc[0], cnt);
    __syncthreads();
    int M = s_misc[0];

    int cutbin = 0;
    if (M > CAP) {
        // histogram-select a score cutoff so kept-count <= CAP.
        // only the top ~1152 candidates can influence the result (each accepted
        // pick suppresses at most its 8 grid neighbors), so a prefix of >=CAP
        // candidates is more than sufficient.
        for (int i = tid; i < 2048; i += 1024) s_idx[i] = 0;
        __syncthreads();
        for (int i = tid; i < N3; i += 1024) {
            float s = sc[i];
            if (s > 0.f) {
                int b = (int)((s - 0.6f) * 5120.f);
                b = b < 0 ? 0 : (b > 2047 ? 2047 : b);
                atomicAdd(&s_idx[b], 1);
            }
        }
        __syncthreads();
        if (tid == 0) {
            int accum = 0, b = 2047;
            for (; b >= 0; --b) {
                int c = s_idx[b];
                if (accum + c > CAP) break;
                accum += c;
            }
            s_misc[2] = b + 1;  // keep bins >= b+1
        }
        __syncthreads();
        cutbin = s_misc[2];
        __syncthreads();        // done with histogram; s_idx reused below
    }

    // compact candidates into LDS
    for (int i = tid; i < N3; i += 1024) {
        float s = sc[i];
        if (s > 0.f) {
            bool keep = true;
            if (M > CAP) {
                int b = (int)((s - 0.6f) * 5120.f);
                b = b < 0 ? 0 : (b > 2047 ? 2047 : b);
                keep = (b >= cutbin);
            }
            if (keep) {
                int pos = atomicAdd(&s_misc[1], 1);
                if (pos < CAP) { s_score[pos] = s; s_idx[pos] = i; }
            }
        }
    }
    __syncthreads();
    int M2 = s_misc[1]; if (M2 > CAP) M2 = CAP;

    // iterative argmax + suppress (tie-break: lowest original index, like jnp.argmax)
    int np = 0;
    for (int pick = 0; pick < KP; ++pick) {
        float bs = -INFINITY; int bi = 0x7fffffff;
        for (int i = tid; i < M2; i += 1024) {
            float s = s_score[i]; int id = s_idx[i];
            if (s > bs || (s == bs && id < bi)) { bs = s; bi = id; }
        }
        #pragma unroll
        for (int off = 32; off; off >>= 1) {
            float os = __shfl_down(bs, off);
            int   oi = __shfl_down(bi, off);
            if (os > bs || (os == bs && oi < bi)) { bs = os; bi = oi; }
        }
        int lane = tid & 63, wv = tid >> 6;
        if (lane == 0) { r_s[wv] = bs; r_i[wv] = bi; }
        __syncthreads();
        if (tid == 0) {
            float ps = r_s[0]; int pi = r_i[0];
            for (int k = 1; k < 16; ++k) {
                float os = r_s[k]; int oi = r_i[k];
                if (os > ps || (os == ps && oi < pi)) { ps = os; pi = oi; }
            }
            s_picks[pick] = ps; s_picki[pick] = pi;
            r_s[0] = ps; r_i[0] = pi;
        }
        __syncthreads();
        float ps = r_s[0]; int pi = r_i[0];
        if (ps < 0.f) break;   // no live candidates remain (uniform across block)
        np = pick + 1;

        // suppress IoU > 0.5 (includes the picked box itself, IoU=1)
        int pcx = pi % W3, pcy = pi / W3;
        float px1 = (float)(2 * pcx + 1), py1 = (float)(2 * pcy + 1);
        float px2 = (float)(2 * pcx + 12), py2 = (float)(2 * pcy + 12);
        for (int i = tid; i < M2; i += 1024) {
            float s = s_score[i];
            if (s > NEGV * 0.5f) {
                int id = s_idx[i];
                int cx = id % W3, cy = id / W3;
                float x1 = (float)(2 * cx + 1), y1 = (float)(2 * cy + 1);
                float x2 = (float)(2 * cx + 12), y2 = (float)(2 * cy + 12);
                float xx1 = fmaxf(px1, x1), yy1 = fmaxf(py1, y1);
                float xx2 = fminf(px2, x2), yy2 = fminf(py2, y2);
                float inter = fmaxf(0.f, xx2 - xx1 + 1.f) * fmaxf(0.f, yy2 - yy1 + 1.f);
                float iou = inter / (288.f - inter);   // both areas are exactly 144
                if (iou > 0.5f) s_score[i] = NEGV;
            }
        }
        __syncthreads();
    }

    // write all 128 rows (zeros beyond np)
    if (tid < KP) {
        float* o = outp + ((size_t)bb * KP + tid) * 5;
        if (tid < np) {
            int pi = s_picki[tid]; float ps = s_picks[tid];
            int cx = pi % W3, cy = pi / W3;
            float x1 = (float)(2 * cx + 1), y1 = (float)(2 * cy + 1);
            float x2 = (float)(2 * cx + 12), y2 = (float)(2 * cy + 12);
            float4 r = regf[(size_t)bb * N3 + pi];
            float wd = x2 - x1, hh = y2 - y1;           // 11
            float q1 = x1 + r.x * wd, q2 = y1 + r.y * hh;
            float q3 = x2 + r.z * wd, q4 = y2 + r.w * hh;
            float rw = q3 - q1, rh = q4 - q2;
            float L = fmaxf(rw, rh);
            float nx1 = q1 + rw * 0.5f - L * 0.5f;
            float ny1 = q2 + rh * 0.5f - L * 0.5f;
            o[0] = nx1; o[1] = ny1; o[2] = nx1 + L; o[3] = ny1 + L; o[4] = ps;
        } else {
            o[0] = 0.f; o[1] = 0.f; o[2] = 0.f; o[3] = 0.f; o[4] = 0.f;
        }
    }
}

// ---------------- launcher ----------------
extern "C" void kernel_launch(void* const* d_in, const int* in_sizes, int n_in,
                              void* d_out, int out_size, void* d_ws, size_t ws_size,
                              hipStream_t stream) {
    const float* im   = (const float*)d_in[0];
    const float* c1w  = (const float*)d_in[1];
    const float* c1b  = (const float*)d_in[2];
    const float* p1   = (const float*)d_in[3];
    const float* c2w  = (const float*)d_in[4];
    const float* c2b  = (const float*)d_in[5];
    const float* p2   = (const float*)d_in[6];
    const float* c3w  = (const float*)d_in[7];
    const float* c3b  = (const float*)d_in[8];
    const float* p3   = (const float*)d_in[9];
    const float* c41w = (const float*)d_in[10];
    const float* c41b = (const float*)d_in[11];
    const float* c42w = (const float*)d_in[12];
    const float* c42b = (const float*)d_in[13];

    float* ws = (float*)d_ws;
    // region0 [0 .. 7,792,800): pool1 output, later reused for scores+regf
    // region1 [7,792,800 .. ): conv2 output (12,237,312 floats)
    const size_t POOL1_FLOATS = (size_t)BATCH * C1 * P1H * P1W;   // 7,792,800
    float*  pool1  = ws;
    float*  conv2b = ws + POOL1_FLOATS;
    float*  scoresb = ws;                                        // reuse region0
    float4* regfb   = (float4*)(ws + (size_t)BATCH * N3);        // 16B-aligned

    dim3 blk(16, 16);
    k_conv1pool<<<dim3(16, 12, BATCH), blk, 0, stream>>>(im, c1w, c1b, p1, pool1);
    k_conv2   <<<dim3(16, 12, BATCH), blk, 0, stream>>>(pool1, c2w, c2b, p2, conv2b);
    k_conv3heads<<<dim3(16, 12, BATCH), blk, 0, stream>>>(conv2b, c3w, c3b, p3,
                                                          c41w, c41b, c42w, c42b,
                                                          scoresb, regfb);
    k_nms<<<dim3(BATCH), dim3(1024), 0, stream>>>(scoresb, regfb, (float*)d_out);
}

// Round 2
// 267.877 us; speedup vs baseline: 1.3164x; 1.3164x over previous
//
#include <hip/hip_runtime.h>
#include <math.h>

// ---------------- problem constants ----------------
#define BATCH 16
#define IH 384
#define IW 512
#define C1 10
#define P1H 191   // pooled H after conv1(382) / 2
#define P1W 255   // pooled W after conv1(510) / 2
#define C2 16
#define H2 189
#define W2 253
#define C3 32
#define H3 187
#define W3 251
#define N3 (H3*W3)        // 46937
#define KP 128
#define CAP 7680          // max candidates kept for NMS (LDS-resident)
#define NEGV (-1e30f)

// ------------- kernel 1: conv1(3->10,3x3) + PReLU + maxpool2 -------------
// one thread per (b, pool_y, pool_x); computes all 10 channels.
// __launch_bounds__(256,2): relax compiler VGPR cap (40-reg heuristic caused
// accumulator spill traffic in the conv kernels).
__global__ __launch_bounds__(256, 2) void k_conv1pool(
        const float* __restrict__ im, const float* __restrict__ w,
        const float* __restrict__ bia, const float* __restrict__ slope,
        float* __restrict__ outp) {
    int x = blockIdx.x * 16 + threadIdx.x;
    int y = blockIdx.y * 16 + threadIdx.y;
    int bb = blockIdx.z;
    if (x >= P1W || y >= P1H) return;

    float in[3][4][4];
    #pragma unroll
    for (int ci = 0; ci < 3; ++ci) {
        const float* p = im + (((size_t)bb * 3 + ci) * IH + 2 * y) * IW + 2 * x;
        #pragma unroll
        for (int r = 0; r < 4; ++r) {
            const float2* q = (const float2*)(p + (size_t)r * IW);  // 8B-aligned
            float2 a0 = q[0], a1 = q[1];
            in[ci][r][0] = a0.x; in[ci][r][1] = a0.y;
            in[ci][r][2] = a1.x; in[ci][r][3] = a1.y;
        }
    }
    #pragma unroll
    for (int ci = 0; ci < 3; ++ci)
        #pragma unroll
        for (int r = 0; r < 4; ++r)
            #pragma unroll
            for (int c = 0; c < 4; ++c)
                in[ci][r][c] = (in[ci][r][c] - 127.5f) * 0.0078125f;

    #pragma unroll
    for (int oc = 0; oc < C1; ++oc) {
        const float* wo = w + oc * 27;  // uniform -> scalar loads
        float bv = bia[oc], sv = slope[oc];
        float best = -INFINITY;
        #pragma unroll
        for (int py = 0; py < 2; ++py)
            #pragma unroll
            for (int px = 0; px < 2; ++px) {
                float acc = bv;
                #pragma unroll
                for (int ci = 0; ci < 3; ++ci)
                    #pragma unroll
                    for (int ky = 0; ky < 3; ++ky)
                        #pragma unroll
                        for (int kx = 0; kx < 3; ++kx)
                            acc += in[ci][py + ky][px + kx] * wo[(ci * 3 + ky) * 3 + kx];
                float v = acc > 0.f ? acc : sv * acc;   // PReLU then pool-max
                best = fmaxf(best, v);
            }
        outp[(((size_t)bb * C1 + oc) * P1H + y) * P1W + x] = best;
    }
}

// ------------- kernel 2: conv2(10->16,3x3) + PReLU -------------
// register-blocked: each thread computes 2 x-adjacent pixels x 16 oc.
// 32 accumulators + 12-value window live -> needs ~60 VGPR, launch_bounds(256,2)
// allows up to 256 so no spills.
__global__ __launch_bounds__(256, 2) void k_conv2(
        const float* __restrict__ inp, const float* __restrict__ w,
        const float* __restrict__ bia, const float* __restrict__ slope,
        float* __restrict__ outp) {
    int x0 = (blockIdx.x * 64 + threadIdx.x) * 2;
    int y  = blockIdx.y * 4 + threadIdx.y;
    int bb = blockIdx.z;
    if (x0 >= W2 || y >= H2) return;

    float a0[C2], a1[C2];
    #pragma unroll
    for (int oc = 0; oc < C2; ++oc) { a0[oc] = bia[oc]; a1[oc] = bia[oc]; }

    // window col x0+3 may be 1 past the row end at the rightmost position
    bool tail = (x0 + 3 > P1W - 1);

    for (int ci = 0; ci < C1; ++ci) {
        const float* p = inp + (((size_t)bb * C1 + ci) * P1H + y) * P1W + x0;
        float v[3][4];
        #pragma unroll
        for (int r = 0; r < 3; ++r) {
            const float* pr = p + (size_t)r * P1W;
            v[r][0] = pr[0]; v[r][1] = pr[1]; v[r][2] = pr[2];
            v[r][3] = tail ? 0.f : pr[3];
        }
        const float* wc = w + ci * 9;
        #pragma unroll
        for (int oc = 0; oc < C2; ++oc) {
            const float* wo = wc + oc * (C1 * 9);
            float s0 = a0[oc], s1 = a1[oc];
            #pragma unroll
            for (int ky = 0; ky < 3; ++ky)
                #pragma unroll
                for (int kx = 0; kx < 3; ++kx) {
                    float wv = wo[ky * 3 + kx];
                    s0 += v[ky][kx]     * wv;
                    s1 += v[ky][kx + 1] * wv;
                }
            a0[oc] = s0; a1[oc] = s1;
        }
    }
    bool px1 = (x0 + 1 < W2);
    #pragma unroll
    for (int oc = 0; oc < C2; ++oc) {
        float sl = slope[oc];
        float* o = outp + (((size_t)bb * C2 + oc) * H2 + y) * W2 + x0;
        float u0 = a0[oc]; o[0] = u0 > 0.f ? u0 : sl * u0;
        if (px1) { float u1 = a1[oc]; o[1] = u1 > 0.f ? u1 : sl * u1; }
    }
}

// ------------- kernel 3: conv3(16->32,3x3)+PReLU + heads + softmax + mask ----
// register-blocked: 2 x-adjacent pixels x 32 oc = 64 accumulators.
__global__ __launch_bounds__(256, 2) void k_conv3heads(
        const float* __restrict__ inp, const float* __restrict__ w3,
        const float* __restrict__ b3, const float* __restrict__ s3,
        const float* __restrict__ w41, const float* __restrict__ b41,
        const float* __restrict__ w42, const float* __restrict__ b42,
        float* __restrict__ scores, float4* __restrict__ regf) {
    int x0 = (blockIdx.x * 64 + threadIdx.x) * 2;
    int y  = blockIdx.y * 4 + threadIdx.y;
    int bb = blockIdx.z;
    if (x0 >= W3 || y >= H3) return;

    float a0[C3], a1[C3];
    #pragma unroll
    for (int oc = 0; oc < C3; ++oc) { a0[oc] = b3[oc]; a1[oc] = b3[oc]; }

    bool tail = (x0 + 3 > W2 - 1);

    for (int ci = 0; ci < C2; ++ci) {
        const float* p = inp + (((size_t)bb * C2 + ci) * H2 + y) * W2 + x0;
        float v[3][4];
        #pragma unroll
        for (int r = 0; r < 3; ++r) {
            const float* pr = p + (size_t)r * W2;
            v[r][0] = pr[0]; v[r][1] = pr[1]; v[r][2] = pr[2];
            v[r][3] = tail ? 0.f : pr[3];
        }
        const float* wc = w3 + ci * 9;
        #pragma unroll
        for (int oc = 0; oc < C3; ++oc) {
            const float* wo = wc + oc * (C2 * 9);
            float s0 = a0[oc], s1 = a1[oc];
            #pragma unroll
            for (int ky = 0; ky < 3; ++ky)
                #pragma unroll
                for (int kx = 0; kx < 3; ++kx) {
                    float wv = wo[ky * 3 + kx];
                    s0 += v[ky][kx]     * wv;
                    s1 += v[ky][kx + 1] * wv;
                }
            a0[oc] = s0; a1[oc] = s1;
        }
    }
    #pragma unroll
    for (int oc = 0; oc < C3; ++oc) {
        float u0 = a0[oc], u1 = a1[oc], sl = s3[oc];
        a0[oc] = u0 > 0.f ? u0 : sl * u0;
        a1[oc] = u1 > 0.f ? u1 : sl * u1;
    }

    // ---- heads (both pixels) ----
    float l00 = b41[0], l01 = b41[1], l10 = b41[0], l11 = b41[1];
    #pragma unroll
    for (int c = 0; c < C3; ++c) {
        float w0 = w41[c], w1 = w41[C3 + c];
        l00 += a0[c] * w0; l01 += a0[c] * w1;
        l10 += a1[c] * w0; l11 += a1[c] * w1;
    }
    float m0 = fmaxf(l00, l01), m1 = fmaxf(l10, l11);
    float p0 = expf(l01 - m0) / (expf(l00 - m0) + expf(l01 - m0));
    float p1 = expf(l11 - m1) / (expf(l10 - m1) + expf(l11 - m1));

    float r00 = b42[0], r01 = b42[1], r02 = b42[2], r03 = b42[3];
    float r10 = b42[0], r11 = b42[1], r12 = b42[2], r13 = b42[3];
    #pragma unroll
    for (int c = 0; c < C3; ++c) {
        float w0 = w42[c], w1 = w42[C3 + c], w2 = w42[2 * C3 + c], w3v = w42[3 * C3 + c];
        r00 += a0[c] * w0; r01 += a0[c] * w1; r02 += a0[c] * w2; r03 += a0[c] * w3v;
        r10 += a1[c] * w0; r11 += a1[c] * w1; r12 += a1[c] * w2; r13 += a1[c] * w3v;
    }

    size_t n0 = (size_t)bb * N3 + y * W3 + x0;
    scores[n0] = (p0 >= 0.6f) ? p0 : NEGV;
    regf[n0]   = make_float4(r00, r01, r02, r03);
    if (x0 + 1 < W3) {
        scores[n0 + 1] = (p1 >= 0.6f) ? p1 : NEGV;
        regf[n0 + 1]   = make_float4(r10, r11, r12, r13);
    }
}

// ------------- kernel 4: per-image NMS (LDS-resident) + box refine -------------
__global__ __launch_bounds__(1024) void k_nms(
        const float* __restrict__ scores, const float4* __restrict__ regf,
        float* __restrict__ outp) {
    __shared__ float s_score[CAP];
    __shared__ int   s_idx[CAP];     // also reused as 2048-bin histogram
    __shared__ float r_s[16];
    __shared__ int   r_i[16];
    __shared__ float s_picks[KP];
    __shared__ int   s_picki[KP];
    __shared__ int   s_misc[4];

    int tid = threadIdx.x;
    int bb = blockIdx.x;
    const float* sc = scores + (size_t)bb * N3;

    if (tid < 4) s_misc[tid] = 0;
    __syncthreads();

    int cnt = 0;
    for (int i = tid; i < N3; i += 1024) if (sc[i] > 0.f) cnt++;
    atomicAdd(&s_misc[0], cnt);
    __syncthreads();
    int M = s_misc[0];

    int cutbin = 0;
    if (M > CAP) {
        for (int i = tid; i < 2048; i += 1024) s_idx[i] = 0;
        __syncthreads();
        for (int i = tid; i < N3; i += 1024) {
            float s = sc[i];
            if (s > 0.f) {
                int b = (int)((s - 0.6f) * 5120.f);
                b = b < 0 ? 0 : (b > 2047 ? 2047 : b);
                atomicAdd(&s_idx[b], 1);
            }
        }
        __syncthreads();
        if (tid == 0) {
            int accum = 0, b = 2047;
            for (; b >= 0; --b) {
                int c = s_idx[b];
                if (accum + c > CAP) break;
                accum += c;
            }
            s_misc[2] = b + 1;
        }
        __syncthreads();
        cutbin = s_misc[2];
        __syncthreads();
    }

    for (int i = tid; i < N3; i += 1024) {
        float s = sc[i];
        if (s > 0.f) {
            bool keep = true;
            if (M > CAP) {
                int b = (int)((s - 0.6f) * 5120.f);
                b = b < 0 ? 0 : (b > 2047 ? 2047 : b);
                keep = (b >= cutbin);
            }
            if (keep) {
                int pos = atomicAdd(&s_misc[1], 1);
                if (pos < CAP) { s_score[pos] = s; s_idx[pos] = i; }
            }
        }
    }
    __syncthreads();
    int M2 = s_misc[1]; if (M2 > CAP) M2 = CAP;

    int np = 0;
    for (int pick = 0; pick < KP; ++pick) {
        float bs = -INFINITY; int bi = 0x7fffffff;
        for (int i = tid; i < M2; i += 1024) {
            float s = s_score[i]; int id = s_idx[i];
            if (s > bs || (s == bs && id < bi)) { bs = s; bi = id; }
        }
        #pragma unroll
        for (int off = 32; off; off >>= 1) {
            float os = __shfl_down(bs, off);
            int   oi = __shfl_down(bi, off);
            if (os > bs || (os == bs && oi < bi)) { bs = os; bi = oi; }
        }
        int lane = tid & 63, wv = tid >> 6;
        if (lane == 0) { r_s[wv] = bs; r_i[wv] = bi; }
        __syncthreads();
        if (tid == 0) {
            float ps = r_s[0]; int pi = r_i[0];
            for (int k = 1; k < 16; ++k) {
                float os = r_s[k]; int oi = r_i[k];
                if (os > ps || (os == ps && oi < pi)) { ps = os; pi = oi; }
            }
            s_picks[pick] = ps; s_picki[pick] = pi;
            r_s[0] = ps; r_i[0] = pi;
        }
        __syncthreads();
        float ps = r_s[0]; int pi = r_i[0];
        if (ps < 0.f) break;
        np = pick + 1;

        int pcx = pi % W3, pcy = pi / W3;
        float px1 = (float)(2 * pcx + 1), py1 = (float)(2 * pcy + 1);
        float px2 = (float)(2 * pcx + 12), py2 = (float)(2 * pcy + 12);
        for (int i = tid; i < M2; i += 1024) {
            float s = s_score[i];
            if (s > NEGV * 0.5f) {
                int id = s_idx[i];
                int cx = id % W3, cy = id / W3;
                float x1 = (float)(2 * cx + 1), y1 = (float)(2 * cy + 1);
                float x2 = (float)(2 * cx + 12), y2 = (float)(2 * cy + 12);
                float xx1 = fmaxf(px1, x1), yy1 = fmaxf(py1, y1);
                float xx2 = fminf(px2, x2), yy2 = fminf(py2, y2);
                float inter = fmaxf(0.f, xx2 - xx1 + 1.f) * fmaxf(0.f, yy2 - yy1 + 1.f);
                float iou = inter / (288.f - inter);
                if (iou > 0.5f) s_score[i] = NEGV;
            }
        }
        __syncthreads();
    }

    if (tid < KP) {
        float* o = outp + ((size_t)bb * KP + tid) * 5;
        if (tid < np) {
            int pi = s_picki[tid]; float ps = s_picks[tid];
            int cx = pi % W3, cy = pi / W3;
            float x1 = (float)(2 * cx + 1), y1 = (float)(2 * cy + 1);
            float x2 = (float)(2 * cx + 12), y2 = (float)(2 * cy + 12);
            float4 r = regf[(size_t)bb * N3 + pi];
            float wd = x2 - x1, hh = y2 - y1;
            float q1 = x1 + r.x * wd, q2 = y1 + r.y * hh;
            float q3 = x2 + r.z * wd, q4 = y2 + r.w * hh;
            float rw = q3 - q1, rh = q4 - q2;
            float L = fmaxf(rw, rh);
            float nx1 = q1 + rw * 0.5f - L * 0.5f;
            float ny1 = q2 + rh * 0.5f - L * 0.5f;
            o[0] = nx1; o[1] = ny1; o[2] = nx1 + L; o[3] = ny1 + L; o[4] = ps;
        } else {
            o[0] = 0.f; o[1] = 0.f; o[2] = 0.f; o[3] = 0.f; o[4] = 0.f;
        }
    }
}

// ---------------- launcher ----------------
extern "C" void kernel_launch(void* const* d_in, const int* in_sizes, int n_in,
                              void* d_out, int out_size, void* d_ws, size_t ws_size,
                              hipStream_t stream) {
    const float* im   = (const float*)d_in[0];
    const float* c1w  = (const float*)d_in[1];
    const float* c1b  = (const float*)d_in[2];
    const float* p1   = (const float*)d_in[3];
    const float* c2w  = (const float*)d_in[4];
    const float* c2b  = (const float*)d_in[5];
    const float* p2   = (const float*)d_in[6];
    const float* c3w  = (const float*)d_in[7];
    const float* c3b  = (const float*)d_in[8];
    const float* p3   = (const float*)d_in[9];
    const float* c41w = (const float*)d_in[10];
    const float* c41b = (const float*)d_in[11];
    const float* c42w = (const float*)d_in[12];
    const float* c42b = (const float*)d_in[13];

    float* ws = (float*)d_ws;
    const size_t POOL1_FLOATS = (size_t)BATCH * C1 * P1H * P1W;   // 7,792,800
    float*  pool1  = ws;
    float*  conv2b = ws + POOL1_FLOATS;
    float*  scoresb = ws;                                        // reuse region0
    float4* regfb   = (float4*)(ws + (size_t)BATCH * N3);        // 16B-aligned

    k_conv1pool<<<dim3(16, 12, BATCH), dim3(16, 16), 0, stream>>>(im, c1w, c1b, p1, pool1);
    k_conv2   <<<dim3(2, 48, BATCH), dim3(64, 4), 0, stream>>>(pool1, c2w, c2b, p2, conv2b);
    k_conv3heads<<<dim3(2, 47, BATCH), dim3(64, 4), 0, stream>>>(conv2b, c3w, c3b, p3,
                                                                 c41w, c41b, c42w, c42b,
                                                                 scoresb, regfb);
    k_nms<<<dim3(BATCH), dim3(1024), 0, stream>>>(scoresb, regfb, (float*)d_out);
}